// Round 17
// baseline (678.753 us; speedup 1.0000x reference)
//
#include <hip/hip_runtime.h>
#include <hip/hip_bf16.h>
#include <cstddef>

typedef __attribute__((ext_vector_type(8))) short bf16x8;
typedef __attribute__((ext_vector_type(4))) float f32x4;

__device__ __forceinline__ unsigned short f2bf(float f) {
    __hip_bfloat16 h = __float2bfloat16(f);
    return __builtin_bit_cast(unsigned short, h);
}
__device__ __forceinline__ float bf2f(unsigned short u) {
    return __bfloat162float(__builtin_bit_cast(__hip_bfloat16, u));
}
__device__ __forceinline__ float bflo(unsigned u) {
    return __builtin_bit_cast(float, u << 16);
}
__device__ __forceinline__ float bfhi(unsigned u) {
    return __builtin_bit_cast(float, u & 0xffff0000u);
}

// ---------------- zero fill ----------------

__global__ void k_zero_i(int* __restrict__ p, int total) {
    int i = blockIdx.x * blockDim.x + threadIdx.x;
    int stride = gridDim.x * blockDim.x;
    for (; i < total; i += stride) p[i] = 0;
}

// ---------------- degree ----------------

__global__ void k_deg_i(const int* __restrict__ dst, int* __restrict__ deg, int E) {
    int e = blockIdx.x * blockDim.x + threadIdx.x;
    if (e < E) atomicAdd(&deg[dst[e]], 1);
}

// ---------------- exclusive scan (dinv fused into scan1) ----------------

#define SCAN_B 1024

__global__ void k_scan1(const int* __restrict__ in, int* __restrict__ out,
                        int* __restrict__ sums, float* __restrict__ dinv, int n) {
    __shared__ int tmp[SCAN_B];
    int tid = threadIdx.x;
    int gid = blockIdx.x * SCAN_B + tid;
    int v = (gid < n) ? in[gid] : 0;
    if (gid < n) dinv[gid] = rsqrtf((float)v + 1.0f);
    tmp[tid] = v;
    __syncthreads();
    for (int off = 1; off < SCAN_B; off <<= 1) {
        int t = (tid >= off) ? tmp[tid - off] : 0;
        __syncthreads();
        tmp[tid] += t;
        __syncthreads();
    }
    if (gid < n) out[gid] = tmp[tid] - v;
    if (tid == SCAN_B - 1) sums[blockIdx.x] = tmp[tid];
}

__global__ void k_scan2(int* __restrict__ sums, int nb) {
    __shared__ int tmp[128];
    int tid = threadIdx.x;
    int v = (tid < nb) ? sums[tid] : 0;
    tmp[tid] = v;
    __syncthreads();
    for (int off = 1; off < 128; off <<= 1) {
        int t = (tid >= off) ? tmp[tid - off] : 0;
        __syncthreads();
        tmp[tid] += t;
        __syncthreads();
    }
    if (tid < nb) sums[tid] = tmp[tid] - v;
}

__global__ void k_scan3(int* __restrict__ out, int* __restrict__ cursor,
                        const int* __restrict__ sums, int n) {
    int gid = blockIdx.x * SCAN_B + threadIdx.x;
    if (gid < n) {
        int v = out[gid] + sums[blockIdx.x];
        out[gid] = v;
        cursor[gid] = v;
    }
}

// ---------------- CSR fill ----------------

__global__ void k_fill(const int* __restrict__ src, const int* __restrict__ dst,
                       int* __restrict__ cursor, int* __restrict__ csr_src, int E) {
    int e = blockIdx.x * blockDim.x + threadIdx.x;
    if (e < E) {
        int pos = atomicAdd(&cursor[dst[e]], 1);
        csr_src[pos] = src[e];
    }
}

// ---------------- all weight conversions in one launch ----------------

__global__ void k_conv_all(const float* __restrict__ W1, const float* __restrict__ W2,
                           const float* __restrict__ Wfc,
                           unsigned short* __restrict__ W1bf, unsigned short* __restrict__ W2bf,
                           unsigned short* __restrict__ Wfch, unsigned short* __restrict__ Wfcl)
{
    int b = blockIdx.x;
    int k = threadIdx.x;                 // 128 threads
    if (b < 128) {
        W1bf[(size_t)b * 128 + k] = f2bf(W1[(size_t)k * 128 + b]);
    } else if (b < 192) {
        int n = b - 128;
        W2bf[(size_t)n * 128 + k] = f2bf(W2[(size_t)k * 64 + n]);
    } else {
        int n = b - 192;                 // 0..999
        if (k < 64) {
            float v = Wfc[(size_t)k * 1000 + n];
            unsigned short hi = f2bf(v);
            Wfch[(size_t)n * 64 + k] = hi;
            Wfcl[(size_t)n * 64 + k] = f2bf(v - bf2f(hi));
        }
    }
}

// ---------------- gather F=128, bf16 in -> bf16 out --------------------------

__device__ __forceinline__ void unpack_fma(float* a, float w, uint4 v) {
    a[0] = fmaf(w, bflo(v.x), a[0]);
    a[1] = fmaf(w, bfhi(v.x), a[1]);
    a[2] = fmaf(w, bflo(v.y), a[2]);
    a[3] = fmaf(w, bfhi(v.y), a[3]);
    a[4] = fmaf(w, bflo(v.z), a[4]);
    a[5] = fmaf(w, bfhi(v.z), a[5]);
    a[6] = fmaf(w, bflo(v.w), a[6]);
    a[7] = fmaf(w, bfhi(v.w), a[7]);
}

__launch_bounds__(256)
__global__ void k_gather128(const unsigned short* __restrict__ hbf,
                            const int* __restrict__ csr_src, const int* __restrict__ off,
                            const float* __restrict__ dinv, const float* __restrict__ bias,
                            unsigned short* __restrict__ obf, int N, int E)
{
    int node = blockIdx.x * 4 + (threadIdx.x >> 6);
    int lane = threadIdx.x & 63;
    if (node >= N) return;
    float dn = dinv[node];
    int beg = off[node];
    int end = (node + 1 < N) ? off[node + 1] : E;

    const int grp = lane >> 4;
    const int sub = lane & 15;

    uint4 sv = make_uint4(0, 0, 0, 0);
    float4 b0 = make_float4(0.f, 0.f, 0.f, 0.f), b1 = b0;
    if (grp == 0) {
        sv = *(const uint4*)(hbf + (size_t)node * 128 + sub * 8);
        b0 = *(const float4*)(bias + sub * 8);
        b1 = *(const float4*)(bias + sub * 8 + 4);
    }

    float a[8] = {0.f, 0.f, 0.f, 0.f, 0.f, 0.f, 0.f, 0.f};
    int i = beg + grp;
    for (; i + 12 < end; i += 16) {
        int s0 = csr_src[i];
        int s1 = csr_src[i + 4];
        int s2 = csr_src[i + 8];
        int s3 = csr_src[i + 12];
        float w0 = dinv[s0] * dn;
        float w1 = dinv[s1] * dn;
        float w2 = dinv[s2] * dn;
        float w3 = dinv[s3] * dn;
        uint4 v0 = *(const uint4*)(hbf + (size_t)s0 * 128 + sub * 8);
        uint4 v1 = *(const uint4*)(hbf + (size_t)s1 * 128 + sub * 8);
        uint4 v2 = *(const uint4*)(hbf + (size_t)s2 * 128 + sub * 8);
        uint4 v3 = *(const uint4*)(hbf + (size_t)s3 * 128 + sub * 8);
        unpack_fma(a, w0, v0);
        unpack_fma(a, w1, v1);
        unpack_fma(a, w2, v2);
        unpack_fma(a, w3, v3);
    }
    for (; i < end; i += 4) {
        int s = csr_src[i];
        float w = dinv[s] * dn;
        uint4 v = *(const uint4*)(hbf + (size_t)s * 128 + sub * 8);
        unpack_fma(a, w, v);
    }

#pragma unroll
    for (int k = 0; k < 8; ++k) {
        a[k] += __shfl_xor(a[k], 16);
        a[k] += __shfl_xor(a[k], 32);
    }

    if (grp == 0) {
        float s[8] = {bflo(sv.x), bfhi(sv.x), bflo(sv.y), bfhi(sv.y),
                      bflo(sv.z), bfhi(sv.z), bflo(sv.w), bfhi(sv.w)};
        float bv[8] = {b0.x, b0.y, b0.z, b0.w, b1.x, b1.y, b1.z, b1.w};
        float w = dn * dn;
        unsigned short o[8];
#pragma unroll
        for (int k = 0; k < 8; ++k)
            o[k] = f2bf(fmaxf(fmaf(s[k], w, a[k]) + bv[k], 0.f));
        uint4 vo;
        vo.x = (unsigned)o[0] | ((unsigned)o[1] << 16);
        vo.y = (unsigned)o[2] | ((unsigned)o[3] << 16);
        vo.z = (unsigned)o[4] | ((unsigned)o[5] << 16);
        vo.w = (unsigned)o[6] | ((unsigned)o[7] << 16);
        *(uint4*)(obf + (size_t)node * 128 + sub * 8) = vo;
    }
}

// ---------------- gather F=64, bf16 in -> split hi/lo out ---------------------

__launch_bounds__(256)
__global__ void k_gather64(const unsigned short* __restrict__ hbf,
                           const int* __restrict__ csr_src, const int* __restrict__ off,
                           const float* __restrict__ dinv, const float* __restrict__ bias,
                           unsigned short* __restrict__ hhi, unsigned short* __restrict__ hlo,
                           int N, int E)
{
    int node = blockIdx.x * 4 + (threadIdx.x >> 6);
    int lane = threadIdx.x & 63;
    if (node >= N) return;
    float dn = dinv[node];
    int beg = off[node];
    int end = (node + 1 < N) ? off[node + 1] : E;

    const int grp = lane >> 3;
    const int sub = lane & 7;

    uint4 sv = make_uint4(0, 0, 0, 0);
    float4 b0 = make_float4(0.f, 0.f, 0.f, 0.f), b1 = b0;
    if (grp == 0) {
        sv = *(const uint4*)(hbf + (size_t)node * 64 + sub * 8);
        b0 = *(const float4*)(bias + sub * 8);
        b1 = *(const float4*)(bias + sub * 8 + 4);
    }

    float a[8] = {0.f, 0.f, 0.f, 0.f, 0.f, 0.f, 0.f, 0.f};
    int i = beg + grp;
    for (; i + 8 < end; i += 16) {
        int s0 = csr_src[i];
        int s1 = csr_src[i + 8];
        float w0 = dinv[s0] * dn;
        float w1 = dinv[s1] * dn;
        uint4 v0 = *(const uint4*)(hbf + (size_t)s0 * 64 + sub * 8);
        uint4 v1 = *(const uint4*)(hbf + (size_t)s1 * 64 + sub * 8);
        unpack_fma(a, w0, v0);
        unpack_fma(a, w1, v1);
    }
    if (i < end) {
        int s = csr_src[i];
        float w = dinv[s] * dn;
        uint4 v = *(const uint4*)(hbf + (size_t)s * 64 + sub * 8);
        unpack_fma(a, w, v);
    }

#pragma unroll
    for (int k = 0; k < 8; ++k) {
        a[k] += __shfl_xor(a[k], 8);
        a[k] += __shfl_xor(a[k], 16);
        a[k] += __shfl_xor(a[k], 32);
    }

    if (grp == 0) {
        float s[8] = {bflo(sv.x), bfhi(sv.x), bflo(sv.y), bfhi(sv.y),
                      bflo(sv.z), bfhi(sv.z), bflo(sv.w), bfhi(sv.w)};
        float bv[8] = {b0.x, b0.y, b0.z, b0.w, b1.x, b1.y, b1.z, b1.w};
        float w = dn * dn;
        unsigned short hi[8], lo[8];
#pragma unroll
        for (int k = 0; k < 8; ++k) {
            float f = fmaxf(fmaf(s[k], w, a[k]) + bv[k], 0.f);
            hi[k] = f2bf(f);
            lo[k] = f2bf(f - bf2f(hi[k]));
        }
        uint4 vh, vl;
        vh.x = (unsigned)hi[0] | ((unsigned)hi[1] << 16);
        vh.y = (unsigned)hi[2] | ((unsigned)hi[3] << 16);
        vh.z = (unsigned)hi[4] | ((unsigned)hi[5] << 16);
        vh.w = (unsigned)hi[6] | ((unsigned)hi[7] << 16);
        vl.x = (unsigned)lo[0] | ((unsigned)lo[1] << 16);
        vl.y = (unsigned)lo[2] | ((unsigned)lo[3] << 16);
        vl.z = (unsigned)lo[4] | ((unsigned)lo[5] << 16);
        vl.w = (unsigned)lo[6] | ((unsigned)lo[7] << 16);
        *(uint4*)(hhi + (size_t)node * 64 + sub * 8) = vh;
        *(uint4*)(hlo + (size_t)node * 64 + sub * 8) = vl;
    }
}

// ---------------- layer-1 GEMM, pure bf16 ----------------

__launch_bounds__(256, 2)
__global__ void gemm_mfma_l1(const float* __restrict__ A,
                             const unsigned short* __restrict__ Bt,
                             unsigned short* __restrict__ Cbf, int M)
{
    __shared__ unsigned short Ah[128 * 64];
    __shared__ unsigned short Bh[128 * 64];

    const int tid = threadIdx.x;
    const int m0 = blockIdx.x * 128;
    const int lane = tid & 63, wave = tid >> 6;
    const int wr = wave >> 1, wc = wave & 1;
    const int lrow = lane & 15, kgrp = lane >> 4;

    f32x4 acc[4][4] = {};

    for (int ph = 0; ph < 2; ++ph) {
        const int k0 = ph * 64;
        __syncthreads();
        {
            const int c4 = tid & 15, r0 = tid >> 4;
#pragma unroll
            for (int p = 0; p < 8; ++p) {
                int row = r0 + p * 16;
                int gr = m0 + row; if (gr >= M) gr = M - 1;
                float4 v = *(const float4*)(A + (size_t)gr * 128 + k0 + c4 * 4);
                ushort4 hv;
                hv.x = f2bf(v.x); hv.y = f2bf(v.y); hv.z = f2bf(v.z); hv.w = f2bf(v.w);
                *(ushort4*)((char*)Ah + row * 128 + ((c4 * 8) ^ ((row & 7) << 4))) = hv;
            }
        }
        {
            const int c = tid & 7, col0 = tid >> 3;
#pragma unroll
            for (int p = 0; p < 4; ++p) {
                int col = col0 + p * 32;
                uint4 v = *(const uint4*)(Bt + (size_t)col * 128 + k0 + c * 8);
                *(uint4*)((char*)Bh + col * 128 + ((c * 16) ^ ((col & 7) << 4))) = v;
            }
        }
        __syncthreads();

#pragma unroll
        for (int ks = 0; ks < 2; ++ks) {
            const int cIdx = kgrp + ks * 4;
            bf16x8 ah[4], bh[4];
#pragma unroll
            for (int i = 0; i < 4; ++i) {
                int row = wr * 64 + i * 16 + lrow;
                ah[i] = *(const bf16x8*)((const char*)Ah + row * 128 + ((cIdx * 16) ^ ((row & 7) << 4)));
            }
#pragma unroll
            for (int j = 0; j < 4; ++j) {
                int col = wc * 64 + j * 16 + lrow;
                bh[j] = *(const bf16x8*)((const char*)Bh + col * 128 + ((cIdx * 16) ^ ((col & 7) << 4)));
            }
#pragma unroll
            for (int i = 0; i < 4; ++i)
#pragma unroll
                for (int j = 0; j < 4; ++j)
                    acc[i][j] = __builtin_amdgcn_mfma_f32_16x16x32_bf16(bh[j], ah[i], acc[i][j], 0, 0, 0);
        }
    }

#pragma unroll
    for (int i = 0; i < 4; ++i) {
        int grow = m0 + wr * 64 + i * 16 + lrow;
        if (grow >= M) continue;
        unsigned short* crow = Cbf + (size_t)grow * 128;
#pragma unroll
        for (int j = 0; j < 4; ++j) {
            int gc = wc * 64 + j * 16 + kgrp * 4;
            ushort4 o;
            o.x = f2bf(acc[i][j][0]);
            o.y = f2bf(acc[i][j][1]);
            o.z = f2bf(acc[i][j][2]);
            o.w = f2bf(acc[i][j][3]);
            *(ushort4*)(crow + gc) = o;
        }
    }
}

// ---------------- layer-2 GEMM, pure bf16 ----------------

__launch_bounds__(256, 3)
__global__ void gemm_mfma_l2(const unsigned short* __restrict__ Abf,
                             const unsigned short* __restrict__ Bt,
                             unsigned short* __restrict__ Cbf, int M)
{
    __shared__ unsigned short Ah[128 * 64];
    __shared__ unsigned short Bh[64 * 64];

    const int tid = threadIdx.x;
    const int m0 = blockIdx.x * 128;
    const int lane = tid & 63, wave = tid >> 6;
    const int wr = wave >> 1, wc = wave & 1;
    const int lrow = lane & 15, kgrp = lane >> 4;

    f32x4 acc[4][2] = {};

    for (int ph = 0; ph < 2; ++ph) {
        const int k0 = ph * 64;
        __syncthreads();
        {
            const int c = tid & 7, r0 = tid >> 3;
#pragma unroll
            for (int p = 0; p < 4; ++p) {
                int row = r0 + p * 32;
                int gr = m0 + row; if (gr >= M) gr = M - 1;
                uint4 v = *(const uint4*)(Abf + (size_t)gr * 128 + k0 + c * 8);
                *(uint4*)((char*)Ah + row * 128 + ((c * 16) ^ ((row & 7) << 4))) = v;
            }
        }
        {
            const int c = tid & 7, col0 = tid >> 3;
#pragma unroll
            for (int p = 0; p < 2; ++p) {
                int col = col0 + p * 32;
                uint4 v = *(const uint4*)(Bt + (size_t)col * 128 + k0 + c * 8);
                *(uint4*)((char*)Bh + col * 128 + ((c * 16) ^ ((col & 7) << 4))) = v;
            }
        }
        __syncthreads();

#pragma unroll
        for (int ks = 0; ks < 2; ++ks) {
            const int cIdx = kgrp + ks * 4;
            bf16x8 ah[4], bh[2];
#pragma unroll
            for (int i = 0; i < 4; ++i) {
                int row = wr * 64 + i * 16 + lrow;
                ah[i] = *(const bf16x8*)((const char*)Ah + row * 128 + ((cIdx * 16) ^ ((row & 7) << 4)));
            }
#pragma unroll
            for (int j = 0; j < 2; ++j) {
                int col = wc * 32 + j * 16 + lrow;
                bh[j] = *(const bf16x8*)((const char*)Bh + col * 128 + ((cIdx * 16) ^ ((col & 7) << 4)));
            }
#pragma unroll
            for (int i = 0; i < 4; ++i)
#pragma unroll
                for (int j = 0; j < 2; ++j)
                    acc[i][j] = __builtin_amdgcn_mfma_f32_16x16x32_bf16(bh[j], ah[i], acc[i][j], 0, 0, 0);
        }
    }

#pragma unroll
    for (int i = 0; i < 4; ++i) {
        int grow = m0 + wr * 64 + i * 16 + lrow;
        if (grow >= M) continue;
        unsigned short* crow = Cbf + (size_t)grow * 64;
#pragma unroll
        for (int j = 0; j < 2; ++j) {
            int gc = wc * 32 + j * 16 + kgrp * 4;
            ushort4 o;
            o.x = f2bf(acc[i][j][0]);
            o.y = f2bf(acc[i][j][1]);
            o.z = f2bf(acc[i][j][2]);
            o.w = f2bf(acc[i][j][3]);
            *(ushort4*)(crow + gc) = o;
        }
    }
}

// ---------------- output MFMA GEMM: LDS-B, 4 M-tiles/block, NT stores --------
// grid (8, 196) = 784 blocks = ONE occupancy pass at 3 blocks/CU; B staged
// once per 4 M-tiles (768 MFMAs per 32 KB stage). C stores nontemporal via
// native ext_vector f32x4 (HIP float4 is rejected by the builtin).

__launch_bounds__(256, 3)
__global__ void gemm_mfma_out(const unsigned short* __restrict__ Ahi,
                              const unsigned short* __restrict__ Alo,
                              const unsigned short* __restrict__ Bhi,
                              const unsigned short* __restrict__ Blo,
                              const float* __restrict__ bias, float* __restrict__ C,
                              int M, int N)
{
    __shared__ unsigned short Bh[128 * 64], Bl[128 * 64];   // 16 KB each

    const int tid = threadIdx.x;
    const int nbase = blockIdx.x * 128;

    // ---- stage B chunk once (swizzled) ----
    {
        const int c = tid & 7, col0 = tid >> 3;
#pragma unroll
        for (int p = 0; p < 4; ++p) {
            int col = col0 + p * 32;
            int gcol = nbase + col; if (gcol >= N) gcol = N - 1;
            uint4 v = *(const uint4*)(Bhi + (size_t)gcol * 64 + c * 8);
            uint4 w = *(const uint4*)(Blo + (size_t)gcol * 64 + c * 8);
            int off = col * 128 + ((c * 16) ^ ((col & 7) << 4));
            *(uint4*)((char*)Bh + off) = v;
            *(uint4*)((char*)Bl + off) = w;
        }
    }
    __syncthreads();

    const int lane = tid & 63, wave = tid >> 6;
    const int wr = wave >> 1, wc = wave & 1;
    const int lrow = lane & 15, kgrp = lane >> 4;
    const int n0 = nbase + wc * 64;

#pragma unroll
    for (int mt = 0; mt < 4; ++mt) {
        const int m0 = (blockIdx.y * 4 + mt) * 128 + wr * 64;
        f32x4 acc[4][4] = {};

#pragma unroll
        for (int ks = 0; ks < 2; ++ks) {
            const int cIdx = kgrp + ks * 4;
            const int koff = cIdx * 8;
            bf16x8 ah[4], al[4], bh[4], bl[4];
#pragma unroll
            for (int i = 0; i < 4; ++i) {
                int row = m0 + i * 16 + lrow; if (row >= M) row = M - 1;
                ah[i] = *(const bf16x8*)(Ahi + (size_t)row * 64 + koff);
                al[i] = *(const bf16x8*)(Alo + (size_t)row * 64 + koff);
            }
#pragma unroll
            for (int j = 0; j < 4; ++j) {
                int col = wc * 64 + j * 16 + lrow;
                int off = col * 128 + ((cIdx * 16) ^ ((col & 7) << 4));
                bh[j] = *(const bf16x8*)((const char*)Bh + off);
                bl[j] = *(const bf16x8*)((const char*)Bl + off);
            }
#pragma unroll
            for (int i = 0; i < 4; ++i)
#pragma unroll
                for (int j = 0; j < 4; ++j) {
                    acc[i][j] = __builtin_amdgcn_mfma_f32_16x16x32_bf16(bh[j], ah[i], acc[i][j], 0, 0, 0);
                    acc[i][j] = __builtin_amdgcn_mfma_f32_16x16x32_bf16(bl[j], ah[i], acc[i][j], 0, 0, 0);
                    acc[i][j] = __builtin_amdgcn_mfma_f32_16x16x32_bf16(bh[j], al[i], acc[i][j], 0, 0, 0);
                }
        }

        // ---- epilogue: nontemporal f32x4 stores ----
#pragma unroll
        for (int i = 0; i < 4; ++i) {
            int grow = m0 + i * 16 + lrow;
            if (grow >= M) continue;
            float* crow = C + (size_t)grow * N;
#pragma unroll
            for (int j = 0; j < 4; ++j) {
                int gc = n0 + j * 16 + kgrp * 4;
                if (gc + 4 <= N) {
                    float4 bv = *(const float4*)(bias + gc);
                    f32x4 o = {acc[i][j][0] + bv.x, acc[i][j][1] + bv.y,
                               acc[i][j][2] + bv.z, acc[i][j][3] + bv.w};
                    __builtin_nontemporal_store(o, (f32x4*)(crow + gc));
                }
            }
        }
    }
}

// ---------------- launch ----------------
// d_out (400 MB) scratch (all dead before final GEMM):
//   hbf[N,128]bf16 | h1bf[N,128]bf16 | h2bf[N,64]bf16 | csr_src[E] | offs |
//   cursor | deg_cnt | bsums
// d_ws (~27 MB): dinv | Wfc hi/lo | W1bf | W2bf | h2hi | h2lo

extern "C" void kernel_launch(void* const* d_in, const int* in_sizes, int n_in,
                              void* d_out, int out_size, void* d_ws, size_t ws_size,
                              hipStream_t stream)
{
    const float* x   = (const float*)d_in[0];
    const float* W1  = (const float*)d_in[1];
    const float* b1  = (const float*)d_in[2];
    const float* W2  = (const float*)d_in[3];
    const float* b2  = (const float*)d_in[4];
    const float* Wfc = (const float*)d_in[5];
    const float* bfc = (const float*)d_in[6];
    const int*   ei  = (const int*)d_in[7];     // int32 in the harness

    const int Nn = in_sizes[0] / 128;      // 100000 nodes
    const int E  = in_sizes[7] / 2;        // 1600000 edges
    const int* src = ei;
    const int* dst = ei + E;

    char* ws = (char*)d_ws;
    float*          dinv   = (float*)(ws);
    unsigned short* Wfc_hi = (unsigned short*)(ws + 512 * 1024);
    unsigned short* Wfc_lo = (unsigned short*)(ws + 768 * 1024);
    unsigned short* W1_bf  = (unsigned short*)(ws + 1024 * 1024);
    unsigned short* W2_bf  = (unsigned short*)(ws + 1088 * 1024);
    unsigned short* h2hi   = (unsigned short*)(ws + 1152 * 1024);
    unsigned short* h2lo   = (unsigned short*)(ws + 1152 * 1024 + (size_t)Nn * 64 * 2);

    char* ob = (char*)d_out;
    unsigned short* hbf     = (unsigned short*)ob;                       // Nn*128 bf16
    unsigned short* h1bf    = (unsigned short*)(ob + (size_t)Nn * 256);  // Nn*128 bf16
    unsigned short* h2bf    = (unsigned short*)(ob + (size_t)Nn * 512);  // Nn*64 bf16
    int*            csr_src = (int*)(ob + (size_t)Nn * 640);             // E ints
    int*            offs    = (int*)((char*)csr_src + (size_t)E * 4);
    int*            cursor  = (int*)((char*)offs + (size_t)Nn * 4);
    int*            deg_cnt = (int*)((char*)cursor + (size_t)Nn * 4);
    int*            bsums   = (int*)((char*)deg_cnt + (size_t)Nn * 4);

    const int nScanBlocks = (Nn + SCAN_B - 1) / SCAN_B;

    // ---- setup: degree, dinv(+scan1), CSR, weight conversion ----
    k_zero_i<<<128, 256, 0, stream>>>(deg_cnt, Nn);
    k_deg_i<<<(E + 255) / 256, 256, 0, stream>>>(dst, deg_cnt, E);
    k_scan1<<<nScanBlocks, SCAN_B, 0, stream>>>(deg_cnt, offs, bsums, dinv, Nn);
    k_scan2<<<1, 128, 0, stream>>>(bsums, nScanBlocks);
    k_scan3<<<nScanBlocks, SCAN_B, 0, stream>>>(offs, cursor, bsums, Nn);
    k_fill<<<(E + 255) / 256, 256, 0, stream>>>(src, dst, cursor, csr_src, E);
    k_conv_all<<<1192, 128, 0, stream>>>(W1, W2, Wfc, W1_bf, W2_bf, Wfc_hi, Wfc_lo);

    // ---- layer 1: hbf = bf16(x @ W1) ----
    gemm_mfma_l1<<<dim3((Nn + 127) / 128, 1), 256, 0, stream>>>(x, W1_bf, hbf, Nn);
    k_gather128<<<(Nn + 3) / 4, 256, 0, stream>>>(hbf, csr_src, offs, dinv, b1,
                                                  h1bf, Nn, E);

    // ---- layer 2: h2bf = bf16(h1 @ W2) ----
    gemm_mfma_l2<<<dim3((Nn + 127) / 128, 1), 256, 0, stream>>>(h1bf, W2_bf, h2bf, Nn);
    k_gather64<<<(Nn + 3) / 4, 256, 0, stream>>>(h2bf, csr_src, offs, dinv, b2,
                                                 h2hi, h2lo, Nn, E);

    // ---- output layer: out = h2 @ Wfc + bfc (LDS-B, 4 M-tiles, NT stores) ----
    gemm_mfma_out<<<dim3(8, (Nn + 511) / 512), 256, 0, stream>>>(
        h2hi, h2lo, Wfc_hi, Wfc_lo, bfc, (float*)d_out, Nn, 1000);
}

// Round 18
// 504.431 us; speedup vs baseline: 1.3456x; 1.3456x over previous
//
#include <hip/hip_runtime.h>
#include <hip/hip_bf16.h>
#include <cstddef>

typedef __attribute__((ext_vector_type(8))) short bf16x8;
typedef __attribute__((ext_vector_type(4))) float f32x4;

__device__ __forceinline__ unsigned short f2bf(float f) {
    __hip_bfloat16 h = __float2bfloat16(f);
    return __builtin_bit_cast(unsigned short, h);
}
__device__ __forceinline__ float bf2f(unsigned short u) {
    return __bfloat162float(__builtin_bit_cast(__hip_bfloat16, u));
}
__device__ __forceinline__ float bflo(unsigned u) {
    return __builtin_bit_cast(float, u << 16);
}
__device__ __forceinline__ float bfhi(unsigned u) {
    return __builtin_bit_cast(float, u & 0xffff0000u);
}

// ---------------- zero fill ----------------

__global__ void k_zero_i(int* __restrict__ p, int total) {
    int i = blockIdx.x * blockDim.x + threadIdx.x;
    int stride = gridDim.x * blockDim.x;
    for (; i < total; i += stride) p[i] = 0;
}

// ---------------- degree ----------------

__global__ void k_deg_i(const int* __restrict__ dst, int* __restrict__ deg, int E) {
    int e = blockIdx.x * blockDim.x + threadIdx.x;
    if (e < E) atomicAdd(&deg[dst[e]], 1);
}

// ---------------- exclusive scan (dinv fused into scan1) ----------------

#define SCAN_B 1024

__global__ void k_scan1(const int* __restrict__ in, int* __restrict__ out,
                        int* __restrict__ sums, float* __restrict__ dinv, int n) {
    __shared__ int tmp[SCAN_B];
    int tid = threadIdx.x;
    int gid = blockIdx.x * SCAN_B + tid;
    int v = (gid < n) ? in[gid] : 0;
    if (gid < n) dinv[gid] = rsqrtf((float)v + 1.0f);
    tmp[tid] = v;
    __syncthreads();
    for (int off = 1; off < SCAN_B; off <<= 1) {
        int t = (tid >= off) ? tmp[tid - off] : 0;
        __syncthreads();
        tmp[tid] += t;
        __syncthreads();
    }
    if (gid < n) out[gid] = tmp[tid] - v;
    if (tid == SCAN_B - 1) sums[blockIdx.x] = tmp[tid];
}

__global__ void k_scan2(int* __restrict__ sums, int nb) {
    __shared__ int tmp[128];
    int tid = threadIdx.x;
    int v = (tid < nb) ? sums[tid] : 0;
    tmp[tid] = v;
    __syncthreads();
    for (int off = 1; off < 128; off <<= 1) {
        int t = (tid >= off) ? tmp[tid - off] : 0;
        __syncthreads();
        tmp[tid] += t;
        __syncthreads();
    }
    if (tid < nb) sums[tid] = tmp[tid] - v;
}

__global__ void k_scan3(int* __restrict__ out, int* __restrict__ cursor,
                        const int* __restrict__ sums, int n) {
    int gid = blockIdx.x * SCAN_B + threadIdx.x;
    if (gid < n) {
        int v = out[gid] + sums[blockIdx.x];
        out[gid] = v;
        cursor[gid] = v;
    }
}

// ---------------- CSR fill ----------------

__global__ void k_fill(const int* __restrict__ src, const int* __restrict__ dst,
                       int* __restrict__ cursor, int* __restrict__ csr_src, int E) {
    int e = blockIdx.x * blockDim.x + threadIdx.x;
    if (e < E) {
        int pos = atomicAdd(&cursor[dst[e]], 1);
        csr_src[pos] = src[e];
    }
}

// ---------------- all weight conversions in one launch ----------------

__global__ void k_conv_all(const float* __restrict__ W1, const float* __restrict__ W2,
                           const float* __restrict__ Wfc,
                           unsigned short* __restrict__ W1bf, unsigned short* __restrict__ W2bf,
                           unsigned short* __restrict__ Wfch, unsigned short* __restrict__ Wfcl)
{
    int b = blockIdx.x;
    int k = threadIdx.x;                 // 128 threads
    if (b < 128) {
        W1bf[(size_t)b * 128 + k] = f2bf(W1[(size_t)k * 128 + b]);
    } else if (b < 192) {
        int n = b - 128;
        W2bf[(size_t)n * 128 + k] = f2bf(W2[(size_t)k * 64 + n]);
    } else {
        int n = b - 192;                 // 0..999
        if (k < 64) {
            float v = Wfc[(size_t)k * 1000 + n];
            unsigned short hi = f2bf(v);
            Wfch[(size_t)n * 64 + k] = hi;
            Wfcl[(size_t)n * 64 + k] = f2bf(v - bf2f(hi));
        }
    }
}

// ---------------- gather F=128, bf16 in -> bf16 out --------------------------

__device__ __forceinline__ void unpack_fma(float* a, float w, uint4 v) {
    a[0] = fmaf(w, bflo(v.x), a[0]);
    a[1] = fmaf(w, bfhi(v.x), a[1]);
    a[2] = fmaf(w, bflo(v.y), a[2]);
    a[3] = fmaf(w, bfhi(v.y), a[3]);
    a[4] = fmaf(w, bflo(v.z), a[4]);
    a[5] = fmaf(w, bfhi(v.z), a[5]);
    a[6] = fmaf(w, bflo(v.w), a[6]);
    a[7] = fmaf(w, bfhi(v.w), a[7]);
}

__launch_bounds__(256)
__global__ void k_gather128(const unsigned short* __restrict__ hbf,
                            const int* __restrict__ csr_src, const int* __restrict__ off,
                            const float* __restrict__ dinv, const float* __restrict__ bias,
                            unsigned short* __restrict__ obf, int N, int E)
{
    int node = blockIdx.x * 4 + (threadIdx.x >> 6);
    int lane = threadIdx.x & 63;
    if (node >= N) return;
    float dn = dinv[node];
    int beg = off[node];
    int end = (node + 1 < N) ? off[node + 1] : E;

    const int grp = lane >> 4;
    const int sub = lane & 15;

    uint4 sv = make_uint4(0, 0, 0, 0);
    float4 b0 = make_float4(0.f, 0.f, 0.f, 0.f), b1 = b0;
    if (grp == 0) {
        sv = *(const uint4*)(hbf + (size_t)node * 128 + sub * 8);
        b0 = *(const float4*)(bias + sub * 8);
        b1 = *(const float4*)(bias + sub * 8 + 4);
    }

    float a[8] = {0.f, 0.f, 0.f, 0.f, 0.f, 0.f, 0.f, 0.f};
    int i = beg + grp;
    for (; i + 12 < end; i += 16) {
        int s0 = csr_src[i];
        int s1 = csr_src[i + 4];
        int s2 = csr_src[i + 8];
        int s3 = csr_src[i + 12];
        float w0 = dinv[s0] * dn;
        float w1 = dinv[s1] * dn;
        float w2 = dinv[s2] * dn;
        float w3 = dinv[s3] * dn;
        uint4 v0 = *(const uint4*)(hbf + (size_t)s0 * 128 + sub * 8);
        uint4 v1 = *(const uint4*)(hbf + (size_t)s1 * 128 + sub * 8);
        uint4 v2 = *(const uint4*)(hbf + (size_t)s2 * 128 + sub * 8);
        uint4 v3 = *(const uint4*)(hbf + (size_t)s3 * 128 + sub * 8);
        unpack_fma(a, w0, v0);
        unpack_fma(a, w1, v1);
        unpack_fma(a, w2, v2);
        unpack_fma(a, w3, v3);
    }
    for (; i < end; i += 4) {
        int s = csr_src[i];
        float w = dinv[s] * dn;
        uint4 v = *(const uint4*)(hbf + (size_t)s * 128 + sub * 8);
        unpack_fma(a, w, v);
    }

#pragma unroll
    for (int k = 0; k < 8; ++k) {
        a[k] += __shfl_xor(a[k], 16);
        a[k] += __shfl_xor(a[k], 32);
    }

    if (grp == 0) {
        float s[8] = {bflo(sv.x), bfhi(sv.x), bflo(sv.y), bfhi(sv.y),
                      bflo(sv.z), bfhi(sv.z), bflo(sv.w), bfhi(sv.w)};
        float bv[8] = {b0.x, b0.y, b0.z, b0.w, b1.x, b1.y, b1.z, b1.w};
        float w = dn * dn;
        unsigned short o[8];
#pragma unroll
        for (int k = 0; k < 8; ++k)
            o[k] = f2bf(fmaxf(fmaf(s[k], w, a[k]) + bv[k], 0.f));
        uint4 vo;
        vo.x = (unsigned)o[0] | ((unsigned)o[1] << 16);
        vo.y = (unsigned)o[2] | ((unsigned)o[3] << 16);
        vo.z = (unsigned)o[4] | ((unsigned)o[5] << 16);
        vo.w = (unsigned)o[6] | ((unsigned)o[7] << 16);
        *(uint4*)(obf + (size_t)node * 128 + sub * 8) = vo;
    }
}

// ---------------- gather F=64, bf16 in -> split hi/lo out ---------------------

__launch_bounds__(256)
__global__ void k_gather64(const unsigned short* __restrict__ hbf,
                           const int* __restrict__ csr_src, const int* __restrict__ off,
                           const float* __restrict__ dinv, const float* __restrict__ bias,
                           unsigned short* __restrict__ hhi, unsigned short* __restrict__ hlo,
                           int N, int E)
{
    int node = blockIdx.x * 4 + (threadIdx.x >> 6);
    int lane = threadIdx.x & 63;
    if (node >= N) return;
    float dn = dinv[node];
    int beg = off[node];
    int end = (node + 1 < N) ? off[node + 1] : E;

    const int grp = lane >> 3;
    const int sub = lane & 7;

    uint4 sv = make_uint4(0, 0, 0, 0);
    float4 b0 = make_float4(0.f, 0.f, 0.f, 0.f), b1 = b0;
    if (grp == 0) {
        sv = *(const uint4*)(hbf + (size_t)node * 64 + sub * 8);
        b0 = *(const float4*)(bias + sub * 8);
        b1 = *(const float4*)(bias + sub * 8 + 4);
    }

    float a[8] = {0.f, 0.f, 0.f, 0.f, 0.f, 0.f, 0.f, 0.f};
    int i = beg + grp;
    for (; i + 8 < end; i += 16) {
        int s0 = csr_src[i];
        int s1 = csr_src[i + 8];
        float w0 = dinv[s0] * dn;
        float w1 = dinv[s1] * dn;
        uint4 v0 = *(const uint4*)(hbf + (size_t)s0 * 64 + sub * 8);
        uint4 v1 = *(const uint4*)(hbf + (size_t)s1 * 64 + sub * 8);
        unpack_fma(a, w0, v0);
        unpack_fma(a, w1, v1);
    }
    if (i < end) {
        int s = csr_src[i];
        float w = dinv[s] * dn;
        uint4 v = *(const uint4*)(hbf + (size_t)s * 64 + sub * 8);
        unpack_fma(a, w, v);
    }

#pragma unroll
    for (int k = 0; k < 8; ++k) {
        a[k] += __shfl_xor(a[k], 8);
        a[k] += __shfl_xor(a[k], 16);
        a[k] += __shfl_xor(a[k], 32);
    }

    if (grp == 0) {
        float s[8] = {bflo(sv.x), bfhi(sv.x), bflo(sv.y), bfhi(sv.y),
                      bflo(sv.z), bfhi(sv.z), bflo(sv.w), bfhi(sv.w)};
        float bv[8] = {b0.x, b0.y, b0.z, b0.w, b1.x, b1.y, b1.z, b1.w};
        float w = dn * dn;
        unsigned short hi[8], lo[8];
#pragma unroll
        for (int k = 0; k < 8; ++k) {
            float f = fmaxf(fmaf(s[k], w, a[k]) + bv[k], 0.f);
            hi[k] = f2bf(f);
            lo[k] = f2bf(f - bf2f(hi[k]));
        }
        uint4 vh, vl;
        vh.x = (unsigned)hi[0] | ((unsigned)hi[1] << 16);
        vh.y = (unsigned)hi[2] | ((unsigned)hi[3] << 16);
        vh.z = (unsigned)hi[4] | ((unsigned)hi[5] << 16);
        vh.w = (unsigned)hi[6] | ((unsigned)hi[7] << 16);
        vl.x = (unsigned)lo[0] | ((unsigned)lo[1] << 16);
        vl.y = (unsigned)lo[2] | ((unsigned)lo[3] << 16);
        vl.z = (unsigned)lo[4] | ((unsigned)lo[5] << 16);
        vl.w = (unsigned)lo[6] | ((unsigned)lo[7] << 16);
        *(uint4*)(hhi + (size_t)node * 64 + sub * 8) = vh;
        *(uint4*)(hlo + (size_t)node * 64 + sub * 8) = vl;
    }
}

// ---------------- layer-1 GEMM, pure bf16 ----------------

__launch_bounds__(256, 2)
__global__ void gemm_mfma_l1(const float* __restrict__ A,
                             const unsigned short* __restrict__ Bt,
                             unsigned short* __restrict__ Cbf, int M)
{
    __shared__ unsigned short Ah[128 * 64];
    __shared__ unsigned short Bh[128 * 64];

    const int tid = threadIdx.x;
    const int m0 = blockIdx.x * 128;
    const int lane = tid & 63, wave = tid >> 6;
    const int wr = wave >> 1, wc = wave & 1;
    const int lrow = lane & 15, kgrp = lane >> 4;

    f32x4 acc[4][4] = {};

    for (int ph = 0; ph < 2; ++ph) {
        const int k0 = ph * 64;
        __syncthreads();
        {
            const int c4 = tid & 15, r0 = tid >> 4;
#pragma unroll
            for (int p = 0; p < 8; ++p) {
                int row = r0 + p * 16;
                int gr = m0 + row; if (gr >= M) gr = M - 1;
                float4 v = *(const float4*)(A + (size_t)gr * 128 + k0 + c4 * 4);
                ushort4 hv;
                hv.x = f2bf(v.x); hv.y = f2bf(v.y); hv.z = f2bf(v.z); hv.w = f2bf(v.w);
                *(ushort4*)((char*)Ah + row * 128 + ((c4 * 8) ^ ((row & 7) << 4))) = hv;
            }
        }
        {
            const int c = tid & 7, col0 = tid >> 3;
#pragma unroll
            for (int p = 0; p < 4; ++p) {
                int col = col0 + p * 32;
                uint4 v = *(const uint4*)(Bt + (size_t)col * 128 + k0 + c * 8);
                *(uint4*)((char*)Bh + col * 128 + ((c * 16) ^ ((col & 7) << 4))) = v;
            }
        }
        __syncthreads();

#pragma unroll
        for (int ks = 0; ks < 2; ++ks) {
            const int cIdx = kgrp + ks * 4;
            bf16x8 ah[4], bh[4];
#pragma unroll
            for (int i = 0; i < 4; ++i) {
                int row = wr * 64 + i * 16 + lrow;
                ah[i] = *(const bf16x8*)((const char*)Ah + row * 128 + ((cIdx * 16) ^ ((row & 7) << 4)));
            }
#pragma unroll
            for (int j = 0; j < 4; ++j) {
                int col = wc * 64 + j * 16 + lrow;
                bh[j] = *(const bf16x8*)((const char*)Bh + col * 128 + ((cIdx * 16) ^ ((col & 7) << 4)));
            }
#pragma unroll
            for (int i = 0; i < 4; ++i)
#pragma unroll
                for (int j = 0; j < 4; ++j)
                    acc[i][j] = __builtin_amdgcn_mfma_f32_16x16x32_bf16(bh[j], ah[i], acc[i][j], 0, 0, 0);
        }
    }

#pragma unroll
    for (int i = 0; i < 4; ++i) {
        int grow = m0 + wr * 64 + i * 16 + lrow;
        if (grow >= M) continue;
        unsigned short* crow = Cbf + (size_t)grow * 128;
#pragma unroll
        for (int j = 0; j < 4; ++j) {
            int gc = wc * 64 + j * 16 + kgrp * 4;
            ushort4 o;
            o.x = f2bf(acc[i][j][0]);
            o.y = f2bf(acc[i][j][1]);
            o.z = f2bf(acc[i][j][2]);
            o.w = f2bf(acc[i][j][3]);
            *(ushort4*)(crow + gc) = o;
        }
    }
}

// ---------------- layer-2 GEMM, pure bf16 ----------------

__launch_bounds__(256, 3)
__global__ void gemm_mfma_l2(const unsigned short* __restrict__ Abf,
                             const unsigned short* __restrict__ Bt,
                             unsigned short* __restrict__ Cbf, int M)
{
    __shared__ unsigned short Ah[128 * 64];
    __shared__ unsigned short Bh[64 * 64];

    const int tid = threadIdx.x;
    const int m0 = blockIdx.x * 128;
    const int lane = tid & 63, wave = tid >> 6;
    const int wr = wave >> 1, wc = wave & 1;
    const int lrow = lane & 15, kgrp = lane >> 4;

    f32x4 acc[4][2] = {};

    for (int ph = 0; ph < 2; ++ph) {
        const int k0 = ph * 64;
        __syncthreads();
        {
            const int c = tid & 7, r0 = tid >> 3;
#pragma unroll
            for (int p = 0; p < 4; ++p) {
                int row = r0 + p * 32;
                int gr = m0 + row; if (gr >= M) gr = M - 1;
                uint4 v = *(const uint4*)(Abf + (size_t)gr * 128 + k0 + c * 8);
                *(uint4*)((char*)Ah + row * 128 + ((c * 16) ^ ((row & 7) << 4))) = v;
            }
        }
        {
            const int c = tid & 7, col0 = tid >> 3;
#pragma unroll
            for (int p = 0; p < 2; ++p) {
                int col = col0 + p * 32;
                uint4 v = *(const uint4*)(Bt + (size_t)col * 128 + k0 + c * 8);
                *(uint4*)((char*)Bh + col * 128 + ((c * 16) ^ ((col & 7) << 4))) = v;
            }
        }
        __syncthreads();

#pragma unroll
        for (int ks = 0; ks < 2; ++ks) {
            const int cIdx = kgrp + ks * 4;
            bf16x8 ah[4], bh[2];
#pragma unroll
            for (int i = 0; i < 4; ++i) {
                int row = wr * 64 + i * 16 + lrow;
                ah[i] = *(const bf16x8*)((const char*)Ah + row * 128 + ((cIdx * 16) ^ ((row & 7) << 4)));
            }
#pragma unroll
            for (int j = 0; j < 2; ++j) {
                int col = wc * 32 + j * 16 + lrow;
                bh[j] = *(const bf16x8*)((const char*)Bh + col * 128 + ((cIdx * 16) ^ ((col & 7) << 4)));
            }
#pragma unroll
            for (int i = 0; i < 4; ++i)
#pragma unroll
                for (int j = 0; j < 2; ++j)
                    acc[i][j] = __builtin_amdgcn_mfma_f32_16x16x32_bf16(bh[j], ah[i], acc[i][j], 0, 0, 0);
        }
    }

#pragma unroll
    for (int i = 0; i < 4; ++i) {
        int grow = m0 + wr * 64 + i * 16 + lrow;
        if (grow >= M) continue;
        unsigned short* crow = Cbf + (size_t)grow * 64;
#pragma unroll
        for (int j = 0; j < 2; ++j) {
            int gc = wc * 32 + j * 16 + kgrp * 4;
            ushort4 o;
            o.x = f2bf(acc[i][j][0]);
            o.y = f2bf(acc[i][j][1]);
            o.z = f2bf(acc[i][j][2]);
            o.w = f2bf(acc[i][j][3]);
            *(ushort4*)(crow + gc) = o;
        }
    }
}

// ---------------- output MFMA GEMM: LDS-staged B, 2 M-tiles/block ------------
// R15's proven form (505 us total). Regular float4 stores THROUGH L2 —
// R17 measured NT stores serializing on HBM store-retire (MfmaUtil 4.8%,
// dur 323us, WRITE +97MB amplification). Do not reintroduce NT here.

__launch_bounds__(256, 3)
__global__ void gemm_mfma_out(const unsigned short* __restrict__ Ahi,
                              const unsigned short* __restrict__ Alo,
                              const unsigned short* __restrict__ Bhi,
                              const unsigned short* __restrict__ Blo,
                              const float* __restrict__ bias, float* __restrict__ C,
                              int M, int N)
{
    __shared__ unsigned short Bh[128 * 64], Bl[128 * 64];   // 16 KB each

    const int tid = threadIdx.x;
    const int nbase = blockIdx.x * 128;

    // ---- stage B chunk once (swizzled) ----
    {
        const int c = tid & 7, col0 = tid >> 3;
#pragma unroll
        for (int p = 0; p < 4; ++p) {
            int col = col0 + p * 32;
            int gcol = nbase + col; if (gcol >= N) gcol = N - 1;
            uint4 v = *(const uint4*)(Bhi + (size_t)gcol * 64 + c * 8);
            uint4 w = *(const uint4*)(Blo + (size_t)gcol * 64 + c * 8);
            int off = col * 128 + ((c * 16) ^ ((col & 7) << 4));
            *(uint4*)((char*)Bh + off) = v;
            *(uint4*)((char*)Bl + off) = w;
        }
    }
    __syncthreads();

    const int lane = tid & 63, wave = tid >> 6;
    const int wr = wave >> 1, wc = wave & 1;
    const int lrow = lane & 15, kgrp = lane >> 4;
    const int n0 = nbase + wc * 64;

#pragma unroll
    for (int mt = 0; mt < 2; ++mt) {
        const int m0 = (blockIdx.y * 2 + mt) * 128 + wr * 64;
        f32x4 acc[4][4] = {};

#pragma unroll
        for (int ks = 0; ks < 2; ++ks) {
            const int cIdx = kgrp + ks * 4;
            const int koff = cIdx * 8;
            bf16x8 ah[4], al[4], bh[4], bl[4];
#pragma unroll
            for (int i = 0; i < 4; ++i) {
                int row = m0 + i * 16 + lrow; if (row >= M) row = M - 1;
                ah[i] = *(const bf16x8*)(Ahi + (size_t)row * 64 + koff);
                al[i] = *(const bf16x8*)(Alo + (size_t)row * 64 + koff);
            }
#pragma unroll
            for (int j = 0; j < 4; ++j) {
                int col = wc * 64 + j * 16 + lrow;
                int off = col * 128 + ((cIdx * 16) ^ ((col & 7) << 4));
                bh[j] = *(const bf16x8*)((const char*)Bh + off);
                bl[j] = *(const bf16x8*)((const char*)Bl + off);
            }
#pragma unroll
            for (int i = 0; i < 4; ++i)
#pragma unroll
                for (int j = 0; j < 4; ++j) {
                    acc[i][j] = __builtin_amdgcn_mfma_f32_16x16x32_bf16(bh[j], ah[i], acc[i][j], 0, 0, 0);
                    acc[i][j] = __builtin_amdgcn_mfma_f32_16x16x32_bf16(bl[j], ah[i], acc[i][j], 0, 0, 0);
                    acc[i][j] = __builtin_amdgcn_mfma_f32_16x16x32_bf16(bh[j], al[i], acc[i][j], 0, 0, 0);
                }
        }

        // ---- epilogue: regular float4 stores (through L2) ----
#pragma unroll
        for (int i = 0; i < 4; ++i) {
            int grow = m0 + i * 16 + lrow;
            if (grow >= M) continue;
            float* crow = C + (size_t)grow * N;
#pragma unroll
            for (int j = 0; j < 4; ++j) {
                int gc = n0 + j * 16 + kgrp * 4;
                if (gc + 4 <= N) {
                    float4 bv = *(const float4*)(bias + gc);
                    *(float4*)(crow + gc) = make_float4(acc[i][j][0] + bv.x,
                                                        acc[i][j][1] + bv.y,
                                                        acc[i][j][2] + bv.z,
                                                        acc[i][j][3] + bv.w);
                }
            }
        }
    }
}

// ---------------- launch ----------------
// d_out (400 MB) scratch (all dead before final GEMM):
//   hbf[N,128]bf16 | h1bf[N,128]bf16 | h2bf[N,64]bf16 | csr_src[E] | offs |
//   cursor | deg_cnt | bsums
// d_ws (~27 MB): dinv | Wfc hi/lo | W1bf | W2bf | h2hi | h2lo

extern "C" void kernel_launch(void* const* d_in, const int* in_sizes, int n_in,
                              void* d_out, int out_size, void* d_ws, size_t ws_size,
                              hipStream_t stream)
{
    const float* x   = (const float*)d_in[0];
    const float* W1  = (const float*)d_in[1];
    const float* b1  = (const float*)d_in[2];
    const float* W2  = (const float*)d_in[3];
    const float* b2  = (const float*)d_in[4];
    const float* Wfc = (const float*)d_in[5];
    const float* bfc = (const float*)d_in[6];
    const int*   ei  = (const int*)d_in[7];     // int32 in the harness

    const int Nn = in_sizes[0] / 128;      // 100000 nodes
    const int E  = in_sizes[7] / 2;        // 1600000 edges
    const int* src = ei;
    const int* dst = ei + E;

    char* ws = (char*)d_ws;
    float*          dinv   = (float*)(ws);
    unsigned short* Wfc_hi = (unsigned short*)(ws + 512 * 1024);
    unsigned short* Wfc_lo = (unsigned short*)(ws + 768 * 1024);
    unsigned short* W1_bf  = (unsigned short*)(ws + 1024 * 1024);
    unsigned short* W2_bf  = (unsigned short*)(ws + 1088 * 1024);
    unsigned short* h2hi   = (unsigned short*)(ws + 1152 * 1024);
    unsigned short* h2lo   = (unsigned short*)(ws + 1152 * 1024 + (size_t)Nn * 64 * 2);

    char* ob = (char*)d_out;
    unsigned short* hbf     = (unsigned short*)ob;                       // Nn*128 bf16
    unsigned short* h1bf    = (unsigned short*)(ob + (size_t)Nn * 256);  // Nn*128 bf16
    unsigned short* h2bf    = (unsigned short*)(ob + (size_t)Nn * 512);  // Nn*64 bf16
    int*            csr_src = (int*)(ob + (size_t)Nn * 640);             // E ints
    int*            offs    = (int*)((char*)csr_src + (size_t)E * 4);
    int*            cursor  = (int*)((char*)offs + (size_t)Nn * 4);
    int*            deg_cnt = (int*)((char*)cursor + (size_t)Nn * 4);
    int*            bsums   = (int*)((char*)deg_cnt + (size_t)Nn * 4);

    const int nScanBlocks = (Nn + SCAN_B - 1) / SCAN_B;

    // ---- setup: degree, dinv(+scan1), CSR, weight conversion ----
    k_zero_i<<<128, 256, 0, stream>>>(deg_cnt, Nn);
    k_deg_i<<<(E + 255) / 256, 256, 0, stream>>>(dst, deg_cnt, E);
    k_scan1<<<nScanBlocks, SCAN_B, 0, stream>>>(deg_cnt, offs, bsums, dinv, Nn);
    k_scan2<<<1, 128, 0, stream>>>(bsums, nScanBlocks);
    k_scan3<<<nScanBlocks, SCAN_B, 0, stream>>>(offs, cursor, bsums, Nn);
    k_fill<<<(E + 255) / 256, 256, 0, stream>>>(src, dst, cursor, csr_src, E);
    k_conv_all<<<1192, 128, 0, stream>>>(W1, W2, Wfc, W1_bf, W2_bf, Wfc_hi, Wfc_lo);

    // ---- layer 1: hbf = bf16(x @ W1) ----
    gemm_mfma_l1<<<dim3((Nn + 127) / 128, 1), 256, 0, stream>>>(x, W1_bf, hbf, Nn);
    k_gather128<<<(Nn + 3) / 4, 256, 0, stream>>>(hbf, csr_src, offs, dinv, b1,
                                                  h1bf, Nn, E);

    // ---- layer 2: h2bf = bf16(h1 @ W2) ----
    gemm_mfma_l2<<<dim3((Nn + 127) / 128, 1), 256, 0, stream>>>(h1bf, W2_bf, h2bf, Nn);
    k_gather64<<<(Nn + 3) / 4, 256, 0, stream>>>(h2bf, csr_src, offs, dinv, b2,
                                                 h2hi, h2lo, Nn, E);

    // ---- output layer: out = h2 @ Wfc + bfc (LDS-B, 2 M-tiles/block) ----
    gemm_mfma_out<<<dim3(8, (Nn + 255) / 256), 256, 0, stream>>>(
        h2hi, h2lo, Wfc_hi, Wfc_lo, bfc, (float*)d_out, Nn, 1000);
}